// Round 3
// baseline (69.825 us; speedup 1.0000x reference)
//
#include <hip/hip_runtime.h>
#include <hip/hip_bf16.h>

// GraphAggrMLPv2: out[n,m,h] = relu(zW1[n,h] + (x^T W2)[m,h] + b[h])
//   z:[8192,128] x:[128,128] W:[256,4] b:[4]  -- fp32 inputs
//   out:[8192,128,4] fp32 (reference output dtype; round-2 bf16 write gave
//   absmax==max|ref| => harness reads fp32)
// Memory-bound: 4 MiB read (z) + 16 MiB write => ~3.3us roofline @6.3TB/s.
// One fused kernel: 256 blocks x 256 threads, 32 z-rows per block.
// Per-block redundant xW compute (64 KiB x stays L2-resident).

using bf16 = __hip_bfloat16;

union F4 { float4 v; float f[4]; };

// LDS bank swizzle for W rows (phase-C reads are d0-strided).
__device__ __forceinline__ int sw(int r) { return r + (r >> 3); }

__global__ void __launch_bounds__(256) gam_fused(
    const float* __restrict__ z, const float* __restrict__ x,
    const float* __restrict__ W, const float* __restrict__ b,
    float* __restrict__ out)
{
    __shared__ float4 Wf[292];        // swizzled [256 rows][4 heads]
    __shared__ float4 tpart[2][128];  // xW partials (two d-halves)
    __shared__ float4 tvec[128];      // t[m][0..3] = xW + b
    __shared__ float4 zw[32];         // zW for this block's 32 rows

    const int t   = threadIdx.x;
    const int blk = blockIdx.x;

    // ---- issue z loads first (HBM, coalesced 16B/lane; overlap phase A) ----
    // block's z slice: 32 rows x 128 = 1024 float4; chunk c: row=c>>5, d0=(c&31)*4
    const float4* zp = (const float4*)(z + (size_t)blk * 32 * 128);
    F4 a0, a1, a2, a3;
    a0.v = zp[t];          // rows  0..7
    a1.v = zp[t + 256];    // rows  8..15
    a2.v = zp[t + 512];    // rows 16..23
    a3.v = zp[t + 768];    // rows 24..31

    // ---- W -> LDS (swizzled) ----
    Wf[sw(t)] = ((const float4*)W)[t];
    __syncthreads();

    // ---- phase A: xW partials t[m][h] = sum_d x[d][m] * W2[d][h] ----
    // m = t&127, d-half = t>>7. x column reads coalesced; x is L2-resident.
    {
        const int m    = t & 127;
        const int half = t >> 7;
        const float* xp = x + (size_t)(half * 64) * 128 + m;
        float4 acc = make_float4(0.f, 0.f, 0.f, 0.f);
#pragma unroll
        for (int dd = 0; dd < 64; ++dd) {
            float  xv = xp[dd * 128];
            float4 w  = Wf[sw(128 + half * 64 + dd)];  // wave-uniform broadcast
            acc.x = fmaf(xv, w.x, acc.x);
            acc.y = fmaf(xv, w.y, acc.y);
            acc.z = fmaf(xv, w.z, acc.z);
            acc.w = fmaf(xv, w.w, acc.w);
        }
        tpart[half][m] = acc;
    }

    // ---- phase C: zW for 32 rows from registers + shfl reduce ----
    // lane's chunk covers z[row][d0..d0+3]; 32 lanes (same t>>5) share a row.
    {
        const int d0 = (t & 31) * 4;
        float4 p0 = make_float4(0.f,0.f,0.f,0.f);
        float4 p1 = make_float4(0.f,0.f,0.f,0.f);
        float4 p2 = make_float4(0.f,0.f,0.f,0.f);
        float4 p3 = make_float4(0.f,0.f,0.f,0.f);
#pragma unroll
        for (int j = 0; j < 4; ++j) {
            float4 w = Wf[sw(d0 + j)];   // W1 rows
            p0.x = fmaf(a0.f[j], w.x, p0.x); p0.y = fmaf(a0.f[j], w.y, p0.y);
            p0.z = fmaf(a0.f[j], w.z, p0.z); p0.w = fmaf(a0.f[j], w.w, p0.w);
            p1.x = fmaf(a1.f[j], w.x, p1.x); p1.y = fmaf(a1.f[j], w.y, p1.y);
            p1.z = fmaf(a1.f[j], w.z, p1.z); p1.w = fmaf(a1.f[j], w.w, p1.w);
            p2.x = fmaf(a2.f[j], w.x, p2.x); p2.y = fmaf(a2.f[j], w.y, p2.y);
            p2.z = fmaf(a2.f[j], w.z, p2.z); p2.w = fmaf(a2.f[j], w.w, p2.w);
            p3.x = fmaf(a3.f[j], w.x, p3.x); p3.y = fmaf(a3.f[j], w.y, p3.y);
            p3.z = fmaf(a3.f[j], w.z, p3.z); p3.w = fmaf(a3.f[j], w.w, p3.w);
        }
#pragma unroll
        for (int off = 16; off; off >>= 1) {
            p0.x += __shfl_xor(p0.x, off); p0.y += __shfl_xor(p0.y, off);
            p0.z += __shfl_xor(p0.z, off); p0.w += __shfl_xor(p0.w, off);
            p1.x += __shfl_xor(p1.x, off); p1.y += __shfl_xor(p1.y, off);
            p1.z += __shfl_xor(p1.z, off); p1.w += __shfl_xor(p1.w, off);
            p2.x += __shfl_xor(p2.x, off); p2.y += __shfl_xor(p2.y, off);
            p2.z += __shfl_xor(p2.z, off); p2.w += __shfl_xor(p2.w, off);
            p3.x += __shfl_xor(p3.x, off); p3.y += __shfl_xor(p3.y, off);
            p3.z += __shfl_xor(p3.z, off); p3.w += __shfl_xor(p3.w, off);
        }
        if ((t & 31) == 0) {
            const int r = t >> 5;        // 0..7
            zw[r]      = p0;
            zw[r + 8]  = p1;
            zw[r + 16] = p2;
            zw[r + 24] = p3;
        }
    }
    __syncthreads();

    // ---- combine t = tpart0 + tpart1 + b ----
    if (t < 128) {
        float4 bv = *(const float4*)b;
        float4 q0 = tpart[0][t];
        float4 q1 = tpart[1][t];
        float4 tv;
        tv.x = q0.x + q1.x + bv.x;
        tv.y = q0.y + q1.y + bv.y;
        tv.z = q0.z + q1.z + bv.z;
        tv.w = q0.w + q1.w + bv.w;
        tvec[t] = tv;
    }
    __syncthreads();

    // ---- phase D: out4[row][m] = relu(tvec[m] + zw[row]) ----
    // float4 chunk c = it*256+t: row = c>>7 = it*2+(t>>7) (wave-uniform),
    // m = c&127 = t&127 (loop-invariant -> one LDS read).
    {
        const float4 tq = tvec[t & 127];
        float4* op = (float4*)out + (size_t)blk * 4096;   // 32 rows x 128 float4
#pragma unroll
        for (int it = 0; it < 16; ++it) {
            const int row = it * 2 + (t >> 7);
            float4 s = zw[row];                            // LDS broadcast
            float4 v;
            v.x = fmaxf(tq.x + s.x, 0.f);
            v.y = fmaxf(tq.y + s.y, 0.f);
            v.z = fmaxf(tq.z + s.z, 0.f);
            v.w = fmaxf(tq.w + s.w, 0.f);
            op[it * 256 + t] = v;                          // 16B coalesced store
        }
    }
}

extern "C" void kernel_launch(void* const* d_in, const int* in_sizes, int n_in,
                              void* d_out, int out_size, void* d_ws, size_t ws_size,
                              hipStream_t stream) {
    const float* z = (const float*)d_in[0];
    const float* x = (const float*)d_in[1];
    const float* W = (const float*)d_in[2];
    const float* b = (const float*)d_in[3];
    float* out = (float*)d_out;
    gam_fused<<<256, 256, 0, stream>>>(z, x, W, b, out);
}